// Round 10
// baseline (226.744 us; speedup 1.0000x reference)
//
#include <hip/hip_runtime.h>
#include <hip/hip_bf16.h>

typedef __hip_bfloat16 bf16;
typedef unsigned short ushort8v __attribute__((ext_vector_type(8)));
typedef short  s16x4  __attribute__((ext_vector_type(4)));
typedef short  bf16x8 __attribute__((ext_vector_type(8)));   // 8 bf16 (4 VGPRs)
typedef float  f32x4  __attribute__((ext_vector_type(4)));

#define HW 4096
#define IMG_W 64

__device__ __forceinline__ float bfbits2f(unsigned short u) {
    return __uint_as_float(((unsigned int)u) << 16);
}
__device__ __forceinline__ short f2bs(float f) {
    bf16 h = __float2bfloat16(f);
    return *reinterpret_cast<short*>(&h);
}

// async global->LDS, 16B per lane (wave-uniform LDS base + lane*16 scatter).
__device__ __forceinline__ void gl_lds16(const void* g, void* s) {
    __builtin_amdgcn_global_load_lds(
        (const __attribute__((address_space(1))) unsigned int*)g,
        (__attribute__((address_space(3))) unsigned int*)s, 16, 0, 0);
}

// ---------------------------------------------------------------------------
// pack_input (device body): concat(gar,cond) fp32 [512][4096] -> inp_t bf16
// [4096][512] pixel-major. inp_t[:,0:256] doubles as gar_t for warp kernel.
// ---------------------------------------------------------------------------
__device__ void pack_input_dev(const float* __restrict__ gar,
                               const float* __restrict__ cond,
                               short* __restrict__ outp, int bx2, float* tile)
{
    // tile: float [32][33] (4224 B) carved from shared buffer
    int bx = bx2 & 127;                // px tile (128)
    int by = bx2 >> 7;                 // ch tile (16)
    int tx = threadIdx.x & 31;
    int ty = threadIdx.x >> 5;
#pragma unroll
    for (int i = 0; i < 4; ++i) {
        int c = by * 32 + ty + i * 8;
        const float* src = (c < 256) ? (gar + (size_t)c * HW)
                                     : (cond + (size_t)(c - 256) * HW);
        tile[(ty + i * 8) * 33 + tx] = src[bx * 32 + tx];
    }
    __syncthreads();
#pragma unroll
    for (int i = 0; i < 4; ++i) {
        int p = bx * 32 + ty + i * 8;
        outp[(size_t)p * 512 + by * 32 + tx] = f2bs(tile[tx * 33 + ty + i * 8]);
    }
}

// ---------------------------------------------------------------------------
// pack_w (device body): W fp32 [G][CREAL][CIN][3][3] -> bf16 blocks, layout
// [g][nt][cc][tap 9][q 4][oc BN][8 ic]  (unit = 16 B; q = ic/8 quarter;
// oc zero-padded beyond CREAL). BLKB = 9*4*BN*16 bytes (no ic pad).
// Conflict-free for the conv kernel: wF lane l15 -> oc-consecutive units.
// ---------------------------------------------------------------------------
template<int CIN, int CREAL, int BN, int NT>
__device__ void pack_w_dev(const float* __restrict__ wgt, char* __restrict__ wp,
                           int bx, short* sT)
{
    constexpr int NCC  = CIN / 32;
    constexpr int BLKB = 9 * 4 * BN * 16;

    const int t  = threadIdx.x;
    const int cc = bx % NCC;
    const int nt = (bx / NCC) % NT;
    const int g  = bx / (NT * NCC);

    for (int i = t; i < BLKB / 8; i += 256)
        reinterpret_cast<s16x4*>(sT)[i] = s16x4{0, 0, 0, 0};
    __syncthreads();

    int ocmax = CREAL - nt * BN; if (ocmax > BN) ocmax = BN;
    const size_t base = ((size_t)(g * CREAL + nt * BN) * CIN + cc * 32) * 9;
    for (int i = t; i < ocmax * 288; i += 256) {
        int oc = i / 288;
        int r  = i % 288;                      // ic*9 + tap
        int ic = r / 9, tap = r % 9;
        sT[(size_t)(((tap * 4 + (ic >> 3)) * BN + oc) * 8 + (ic & 7))] =
            f2bs(wgt[base + (size_t)oc * CIN * 9 + r]);
    }
    __syncthreads();

    const s16x4* src = reinterpret_cast<const s16x4*>(sT);
    s16x4* dst = reinterpret_cast<s16x4*>(wp + (size_t)bx * BLKB);
    for (int i = t; i < BLKB / 8; i += 256)
        dst[i] = src[i];
}

// All packing in one launch (block-range dispatch; branch is block-uniform).
__global__ __launch_bounds__(256)
void pack_all(const float* __restrict__ gar, const float* __restrict__ cond,
              const float* __restrict__ W1, const float* __restrict__ W2,
              const float* __restrict__ W3, const float* __restrict__ W4,
              short* inp_t, char* W1p, char* W2p, char* W3p, char* W4p)
{
    __shared__ __align__(16) short sbuf[9 * 4 * 64 * 8];   // 36864 B
    int bx = blockIdx.x;
    if (bx < 256)      pack_w_dev<512, 128, 64, 2>(W1, W1p, bx,       sbuf);
    else if (bx < 288) pack_w_dev<128,  64, 64, 1>(W2, W2p, bx - 256, sbuf);
    else if (bx < 304) pack_w_dev< 64,  32, 32, 1>(W3, W3p, bx - 288, sbuf);
    else if (bx < 312) pack_w_dev< 32,  18, 32, 1>(W4, W4p, bx - 304, sbuf);
    else pack_input_dev(gar, cond, inp_t, bx - 312, (float*)sbuf);
}

// ---------------------------------------------------------------------------
// Implicit-GEMM 3x3 SAME conv, bf16 MFMA 16x16x32, conflict-free LDS.
// sA[row][q][68 cols][8]: pF lane l15 -> col-consecutive 16B units.
// sB[tap][q][oc][8]   : wF lane l15 -> oc-consecutive 16B units (DMA-staged,
// double-buffered: stageB(cc+1) issued at top of phase cc -> barrier drains
// wait on loads issued a full phase earlier).
// sA staged via per-col 64B global loads -> col-consecutive LDS writes.
// ---------------------------------------------------------------------------
template<int ICP, int CREAL, int BN, int ROWS, int OF, int NT,
         bool PIXMAJ_OUT, bool LEAKY, bool OUT_F32>
__global__ __launch_bounds__(256, 2)
void conv_mfma(const short* __restrict__ inp, const char* __restrict__ wp,
               const float* __restrict__ bias, void* __restrict__ outv)
{
    constexpr int NCC  = ICP / 32;
    constexpr int HALO = ROWS + 2;
    constexpr int NPT  = 4096 / (ROWS * 64);
    constexpr int BLKB = 9 * 4 * BN * 16;
    constexpr int RNDS = BLKB / 1024;
    constexpr int NBUF = (NCC > 1) ? 2 : 1;

    __shared__ __align__(16) short sA[HALO][4][68][8];
    __shared__ __align__(16) char  sBraw[NBUF][BLKB];

    const int b  = blockIdx.x;
    const int g  = b & 7;                     // XCD swizzle: group per XCD
    const int r_ = b >> 3;
    const int pt = r_ % NPT;
    const int nt = r_ / NPT;
    const int r0 = pt * ROWS;

    const int t    = threadIdx.x;
    const int wave = t >> 6, lane = t & 63;
    const int l15  = lane & 15, quad = lane >> 4;
    const int row_l = (ROWS == 4) ? wave : (wave & 1);
    const int ocw   = (ROWS == 4) ? 0 : (wave >> 1) * (BN / 2);

    const size_t gpix = (ICP == 512) ? 0 : ((size_t)g * 4096);
    const char*  wb   = wp + (size_t)((g * NT + nt) * NCC) * BLKB;

    // sA staging: thread -> (col, r2); each handles rows {r2, r2+4}∩[0,HALO)
    const int acol = t & 63;
    const int r2   = t >> 6;

    bf16x8 pre[2][4];

    auto stageA_load = [&](int cc) {
#pragma unroll
        for (int s = 0; s < 2; ++s) {
            int j = r2 + s * 4;
            if (j < HALO) {
                int gy = r0 - 1 + j;
                if (gy >= 0 && gy < 64) {
                    const short* sp = inp + ((gpix + gy * 64 + acol) * ICP + cc * 32);
#pragma unroll
                    for (int q = 0; q < 4; ++q)
                        pre[s][q] = *reinterpret_cast<const bf16x8*>(sp + q * 8);
                } else {
#pragma unroll
                    for (int q = 0; q < 4; ++q)
                        pre[s][q] = bf16x8{0, 0, 0, 0, 0, 0, 0, 0};
                }
            }
        }
    };
    auto stageA_write = [&]() {
#pragma unroll
        for (int s = 0; s < 2; ++s) {
            int j = r2 + s * 4;
            if (j < HALO) {
#pragma unroll
                for (int q = 0; q < 4; ++q)
                    *reinterpret_cast<bf16x8*>(&sA[j][q][acol + 1][0]) = pre[s][q];
            }
        }
    };
    auto stageB = [&](int cc) {
        const char* wsrc = wb + (size_t)cc * BLKB;
        char* sbb = (char*)sBraw[cc & (NBUF - 1)];
        for (int r = wave; r < RNDS; r += 4)
            gl_lds16(wsrc + r * 1024 + lane * 16, sbb + r * 1024);
    };

    f32x4 acc[OF][4];
#pragma unroll
    for (int o = 0; o < OF; ++o)
#pragma unroll
        for (int p = 0; p < 4; ++p)
#pragma unroll
            for (int r = 0; r < 4; ++r) acc[o][p][r] = 0.f;

    // zero the x-pad column units (col index 0 and 65) once
    if (t < HALO * 8) {
        int row = t >> 3, q = (t >> 1) & 3, cp = (t & 1) ? 65 : 0;
        *reinterpret_cast<bf16x8*>(&sA[row][q][cp][0]) =
            bf16x8{0, 0, 0, 0, 0, 0, 0, 0};
    }

    // prologue: stage phase 0
    stageB(0);
    stageA_load(0);
    stageA_write();

    for (int cc = 0; cc < NCC; ++cc) {
        __syncthreads();               // sB(cc) drained (issued a phase ago)
        if (cc + 1 < NCC) {
            stageB(cc + 1);            // DMA into alternate buffer
            stageA_load(cc + 1);       // global -> regs, no LDS touch
        }
        const bf16x8* sBv = reinterpret_cast<const bf16x8*>(sBraw[cc & (NBUF - 1)]);

#pragma unroll
        for (int dy = 0; dy < 3; ++dy) {
#pragma unroll
            for (int dx = 0; dx < 3; ++dx) {
                bf16x8 pF[4];
#pragma unroll
                for (int p = 0; p < 4; ++p)
                    pF[p] = *reinterpret_cast<const bf16x8*>(
                        &sA[row_l + dy][quad][p * 16 + l15 + dx][0]);
                bf16x8 wF[OF];
#pragma unroll
                for (int o = 0; o < OF; ++o)
                    wF[o] = sBv[((dy * 3 + dx) * 4 + quad) * BN + ocw + o * 16 + l15];
#pragma unroll
                for (int o = 0; o < OF; ++o)
#pragma unroll
                    for (int p = 0; p < 4; ++p)
                        acc[o][p] = __builtin_amdgcn_mfma_f32_16x16x32_bf16(
                            wF[o], pF[p], acc[o][p], 0, 0, 0);
            }
        }
        __syncthreads();               // all reads of sA(cc) done
        if (cc + 1 < NCC) stageA_write();
    }

    // ---- epilogue. C/D: m(oc) = quad*4+reg, n(pixel) = l15.
    const int prow = r0 + row_l;
#pragma unroll
    for (int o = 0; o < OF; ++o)
#pragma unroll
        for (int reg = 0; reg < 4; ++reg) {
            const int ocl = ocw + o * 16 + quad * 4 + reg;
            const int ocg = nt * BN + ocl;
            if (ocg < CREAL) {
                const float bv = bias[g * CREAL + ocg];
                if (PIXMAJ_OUT) {
                    short* outp = (short*)outv;
                    const size_t pixbase = ((size_t)g * 4096 + prow * 64);
#pragma unroll
                    for (int p = 0; p < 4; ++p) {
                        float v = acc[o][p][reg] + bv;
                        if (LEAKY) v = v >= 0.f ? v : 0.1f * v;
                        outp[(pixbase + p * 16 + l15) * (NT * BN) + ocg] = f2bs(v);
                    }
                } else if (OUT_F32) {
                    float* outp = (float*)outv;
                    const size_t base = ((size_t)(g * CREAL + ocg)) * HW + prow * IMG_W;
#pragma unroll
                    for (int p = 0; p < 4; ++p) {
                        float v = acc[o][p][reg] + bv;
                        if (LEAKY) v = v >= 0.f ? v : 0.1f * v;
                        outp[base + p * 16 + l15] = v;
                    }
                } else {
                    short* outp = (short*)outv;
                    const size_t base = ((size_t)(g * CREAL + ocg)) * HW + prow * IMG_W;
#pragma unroll
                    for (int p = 0; p < 4; ++p) {
                        float v = acc[o][p][reg] + bv;
                        if (LEAKY) v = v >= 0.f ? v : 0.1f * v;
                        outp[base + p * 16 + l15] = f2bs(v);
                    }
                }
            }
        }
}

// ---------------------------------------------------------------------------
// Fused softmax-over-groups + bilinear params + warp + combine (fp32 out).
// gar channels come from inp_t rows (stride 512, first 256 entries).
// ---------------------------------------------------------------------------
__global__ __launch_bounds__(256)
void warp_combine_kernel(const float* __restrict__ oa,
                         const short* __restrict__ inp_t,
                         const float* __restrict__ mask,
                         float* __restrict__ out)
{
    __shared__ __align__(16) float4 sWts[8][6][8];
    __shared__ __align__(16) int4   sIdx[8][6][8];

    const int t = threadIdx.x;

    if (t < 48) {
        int lp = t / 6;
        int k  = t % 6;
        int p  = blockIdx.x * 8 + lp;
        int x  = p & 63, y = p >> 6;

        float l[8];
        float m = -1e30f;
#pragma unroll
        for (int g = 0; g < 8; ++g) {
            l[g] = oa[(size_t)(g * 18 + 12 + k) * HW + p];
            m = fmaxf(m, l[g]);
        }
        float s = 0.f;
#pragma unroll
        for (int g = 0; g < 8; ++g) { l[g] = __expf(l[g] - m); s += l[g]; }
        float inv = 1.f / s;

#pragma unroll
        for (int g = 0; g < 8; ++g) {
            float a  = l[g] * inv;
            float ox = oa[(size_t)(g * 18 + 2 * k)     * HW + p];
            float oy = oa[(size_t)(g * 18 + 2 * k + 1) * HW + p];
            float sx = fminf(fmaxf(((float)x + ox) * (64.f / 63.f) - 0.5f, 0.f), 63.f);
            float sy = fminf(fmaxf(((float)y + oy) * (64.f / 63.f) - 0.5f, 0.f), 63.f);
            float fx0 = floorf(sx), fy0 = floorf(sy);
            int   x0 = (int)fx0,    y0i = (int)fy0;
            float wx = sx - fx0,    wy = sy - fy0;
            int   x1 = min(x0 + 1, 63), y1 = min(y0i + 1, 63);
            sWts[lp][k][g] = make_float4(a * (1.f - wy) * (1.f - wx),
                                         a * (1.f - wy) * wx,
                                         a * wy * (1.f - wx),
                                         a * wy * wx);
            sIdx[lp][k][g] = make_int4(y0i * 64 + x0, y0i * 64 + x1,
                                       y1  * 64 + x0, y1  * 64 + x1);
        }
    }
    __syncthreads();

    const int lp = t >> 5;
    const int p  = blockIdx.x * 8 + lp;
    const int c0 = (t & 31) * 8;

    float acc[8];
#pragma unroll
    for (int j = 0; j < 8; ++j) acc[j] = 0.f;

    for (int g = 0; g < 8; ++g) {
        float4 m0 = *reinterpret_cast<const float4*>(mask + g * 256 + c0);
        float4 m1 = *reinterpret_cast<const float4*>(mask + g * 256 + c0 + 4);
        float mk[8] = {m0.x, m0.y, m0.z, m0.w, m1.x, m1.y, m1.z, m1.w};
#pragma unroll
        for (int k = 0; k < 6; ++k) {
            float4 w  = sWts[lp][k][g];
            int4   id = sIdx[lp][k][g];
            ushort8v v00 = *reinterpret_cast<const ushort8v*>(inp_t + (size_t)id.x * 512 + c0);
            ushort8v v01 = *reinterpret_cast<const ushort8v*>(inp_t + (size_t)id.y * 512 + c0);
            ushort8v v10 = *reinterpret_cast<const ushort8v*>(inp_t + (size_t)id.z * 512 + c0);
            ushort8v v11 = *reinterpret_cast<const ushort8v*>(inp_t + (size_t)id.w * 512 + c0);
#pragma unroll
            for (int j = 0; j < 8; ++j) {
                float sv = w.x * bfbits2f(v00[j]) + w.y * bfbits2f(v01[j])
                         + w.z * bfbits2f(v10[j]) + w.w * bfbits2f(v11[j]);
                acc[j] = fmaf(mk[j], sv, acc[j]);
            }
        }
    }
#pragma unroll
    for (int j = 0; j < 8; ++j)
        out[(size_t)(c0 + j) * HW + p] = acc[j];
}

// ---------------------------------------------------------------------------
// Workspace (peak ~25 MB):
//   [0, 4M)        inp_t  bf16 [4096][512]              (live to end)
//   [4M, 13.44M)   W1p    256 x 36864 B                 (dead after conv1)
//       reuse:     hid2_t @4M  bf16 [8][4096][64] (4MB)
//                  hid3_t @8M  bf16 [8][4096][32] (2MB)
//                  oa     @10.5M fp32 [8][18][4096] (2.25MB)
//   [14M, 15.18M)  W2p    32 x 36864 B
//   [15.5M, ...)   W3p    16 x 18432 B
//   [16M, ...)     W4p     8 x 18432 B
//   [17M, 25M)     hid1_t bf16 [8][4096][128]           (dead after conv2)
// ---------------------------------------------------------------------------
extern "C" void kernel_launch(void* const* d_in, const int* in_sizes, int n_in,
                              void* d_out, int out_size, void* d_ws, size_t ws_size,
                              hipStream_t stream)
{
    (void)in_sizes; (void)n_in; (void)out_size; (void)ws_size;
    const float* gar  = (const float*)d_in[0];
    const float* cond = (const float*)d_in[1];
    const float* mask = (const float*)d_in[2];
    const float* W1   = (const float*)d_in[3];
    const float* b1   = (const float*)d_in[4];
    const float* W2   = (const float*)d_in[5];
    const float* b2   = (const float*)d_in[6];
    const float* W3   = (const float*)d_in[7];
    const float* b3   = (const float*)d_in[8];
    const float* W4   = (const float*)d_in[9];
    const float* b4   = (const float*)d_in[10];
    float* out = (float*)d_out;

    char* ws = (char*)d_ws;
    short* inp_t  = (short*)(ws);
    char*  W1p    = ws + (4u << 20);
    short* hid2_t = (short*)(ws + (4u << 20));          // overlays dead W1p
    short* hid3_t = (short*)(ws + (8u << 20));          // overlays dead W1p
    float* oa     = (float*)(ws + (10u << 20) + (512u << 10));
    char*  W2p    = ws + (14u << 20);
    char*  W3p    = ws + (15u << 20) + (512u << 10);
    char*  W4p    = ws + (16u << 20);
    short* hid1_t = (short*)(ws + (17u << 20));

    // 312 weight-pack blocks + 2048 input-transpose blocks, one launch
    pack_all<<<2360, 256, 0, stream>>>(gar, cond, W1, W2, W3, W4,
                                       inp_t, W1p, W2p, W3p, W4p);

    // conv1: 512->128, ROWS=4, BN=64, OF=4, NT=2, pixel-major out, leaky
    conv_mfma<512, 128, 64, 4, 4, 2, true, true, false>
        <<<256, 256, 0, stream>>>(inp_t, W1p, b1, hid1_t);
    // conv2: 128->64, ROWS=2, BN=64, OF=2, NT=1, pixel-major out, leaky
    conv_mfma<128, 64, 64, 2, 2, 1, true, true, false>
        <<<256, 256, 0, stream>>>(hid1_t, W2p, b2, hid2_t);
    // conv3: 64->32, ROWS=2, BN=32, OF=1, NT=1, pixel-major out, leaky
    conv_mfma<64, 32, 32, 2, 1, 1, true, true, false>
        <<<256, 256, 0, stream>>>(hid2_t, W3p, b3, hid3_t);
    // conv4: 32->18 (pad 32), ROWS=2, BN=32, OF=1, NT=1, ch-major fp32, linear
    conv_mfma<32, 18, 32, 2, 1, 1, false, false, true>
        <<<256, 256, 0, stream>>>(hid3_t, W4p, b4, oa);

    warp_combine_kernel<<<512, 256, 0, stream>>>(oa, inp_t, mask, out);
}

// Round 11
// 202.875 us; speedup vs baseline: 1.1177x; 1.1177x over previous
//
#include <hip/hip_runtime.h>
#include <hip/hip_bf16.h>

typedef __hip_bfloat16 bf16;
typedef unsigned short ushort8v __attribute__((ext_vector_type(8)));
typedef short  s16x4  __attribute__((ext_vector_type(4)));
typedef short  bf16x8 __attribute__((ext_vector_type(8)));   // 8 bf16 (4 VGPRs)
typedef float  f32x4  __attribute__((ext_vector_type(4)));

#define HW 4096
#define IMG_W 64

__device__ __forceinline__ float bfbits2f(unsigned short u) {
    return __uint_as_float(((unsigned int)u) << 16);
}
__device__ __forceinline__ short f2bs(float f) {
    bf16 h = __float2bfloat16(f);
    return *reinterpret_cast<short*>(&h);
}

// async global->LDS, 16B per lane (wave-uniform LDS base + lane*16 scatter).
__device__ __forceinline__ void gl_lds16(const void* g, void* s) {
    __builtin_amdgcn_global_load_lds(
        (const __attribute__((address_space(1))) unsigned int*)g,
        (__attribute__((address_space(3))) unsigned int*)s, 16, 0, 0);
}

// ---------------------------------------------------------------------------
// pack_input (device body): concat(gar,cond) fp32 [512][4096] -> inp_t bf16
// [4096][512] pixel-major. inp_t[:,0:256] doubles as gar_t for warp kernel.
// ---------------------------------------------------------------------------
__device__ void pack_input_dev(const float* __restrict__ gar,
                               const float* __restrict__ cond,
                               short* __restrict__ outp, int bx2, float* tile)
{
    int bx = bx2 & 127;                // px tile (128)
    int by = bx2 >> 7;                 // ch tile (16)
    int tx = threadIdx.x & 31;
    int ty = threadIdx.x >> 5;
#pragma unroll
    for (int i = 0; i < 4; ++i) {
        int c = by * 32 + ty + i * 8;
        const float* src = (c < 256) ? (gar + (size_t)c * HW)
                                     : (cond + (size_t)(c - 256) * HW);
        tile[(ty + i * 8) * 33 + tx] = src[bx * 32 + tx];
    }
    __syncthreads();
#pragma unroll
    for (int i = 0; i < 4; ++i) {
        int p = bx * 32 + ty + i * 8;
        outp[(size_t)p * 512 + by * 32 + tx] = f2bs(tile[tx * 33 + ty + i * 8]);
    }
}

// ---------------------------------------------------------------------------
// pack_w (device body): W fp32 [G][CREAL][CIN][3][3] -> bf16 blocks, layout
// [g][nt][cc][tap 9][q 4][oc BN][8 ic]  (unit = 16 B; q = ic/8 quarter;
// oc zero-padded beyond CREAL). BLKB = 9*4*BN*16 bytes.
// ---------------------------------------------------------------------------
template<int CIN, int CREAL, int BN, int NT>
__device__ void pack_w_dev(const float* __restrict__ wgt, char* __restrict__ wp,
                           int bx, short* sT)
{
    constexpr int NCC  = CIN / 32;
    constexpr int BLKB = 9 * 4 * BN * 16;

    const int t  = threadIdx.x;
    const int cc = bx % NCC;
    const int nt = (bx / NCC) % NT;
    const int g  = bx / (NT * NCC);

    for (int i = t; i < BLKB / 8; i += 256)
        reinterpret_cast<s16x4*>(sT)[i] = s16x4{0, 0, 0, 0};
    __syncthreads();

    int ocmax = CREAL - nt * BN; if (ocmax > BN) ocmax = BN;
    const size_t base = ((size_t)(g * CREAL + nt * BN) * CIN + cc * 32) * 9;
    for (int i = t; i < ocmax * 288; i += 256) {
        int oc = i / 288;
        int r  = i % 288;                      // ic*9 + tap
        int ic = r / 9, tap = r % 9;
        sT[(size_t)(((tap * 4 + (ic >> 3)) * BN + oc) * 8 + (ic & 7))] =
            f2bs(wgt[base + (size_t)oc * CIN * 9 + r]);
    }
    __syncthreads();

    const s16x4* src = reinterpret_cast<const s16x4*>(sT);
    s16x4* dst = reinterpret_cast<s16x4*>(wp + (size_t)bx * BLKB);
    for (int i = t; i < BLKB / 8; i += 256)
        dst[i] = src[i];
}

// All packing in one launch (block-range dispatch; branch is block-uniform).
__global__ __launch_bounds__(256)
void pack_all(const float* __restrict__ gar, const float* __restrict__ cond,
              const float* __restrict__ W1, const float* __restrict__ W2,
              const float* __restrict__ W3, const float* __restrict__ W4,
              short* inp_t, char* W1p, char* W2p, char* W3p, char* W4p)
{
    __shared__ __align__(16) short sbuf[9 * 4 * 64 * 8];   // 36864 B
    int bx = blockIdx.x;
    if (bx < 256)      pack_w_dev<512, 128, 64, 2>(W1, W1p, bx,       sbuf);
    else if (bx < 288) pack_w_dev<128,  64, 64, 1>(W2, W2p, bx - 256, sbuf);
    else if (bx < 304) pack_w_dev< 64,  32, 32, 1>(W3, W3p, bx - 288, sbuf);
    else if (bx < 312) pack_w_dev< 32,  18, 32, 1>(W4, W4p, bx - 304, sbuf);
    else pack_input_dev(gar, cond, inp_t, bx - 312, (float*)sbuf);
}

// ---------------------------------------------------------------------------
// Implicit-GEMM 3x3 SAME conv, bf16 MFMA 16x16x32, conflict-free LDS,
// NW waves per block (NW=8 -> 2 waves/SIMD: the latency-hiding lever).
// Wave mapping:
//   NW=8, ROWS=4: wave -> (row = wave>>1, oc-half = wave&1),   OF=BN/32
//   NW=8, ROWS=2: wave -> (row = wave>>2, oc-quarter = wave&3),OF=BN/64
//   NW=4, ROWS=4: wave -> row, full BN                          OF=BN/16
//   NW=4, ROWS=2: wave -> (row, oc-half)                        OF=BN/32
// sB DMA double-buffered: stageB(cc+1) issued at top of phase cc so barrier
// drains wait on loads issued a full phase earlier.
// ---------------------------------------------------------------------------
template<int ICP, int CREAL, int BN, int ROWS, int OF, int NT, int NW,
         bool PIXMAJ_OUT, bool LEAKY, bool OUT_F32>
__global__ __launch_bounds__(NW * 64, 2)
void conv_mfma(const short* __restrict__ inp, const char* __restrict__ wp,
               const float* __restrict__ bias, void* __restrict__ outv)
{
    constexpr int NCC  = ICP / 32;
    constexpr int HALO = ROWS + 2;
    constexpr int NPT  = 4096 / (ROWS * 64);
    constexpr int BLKB = 9 * 4 * BN * 16;
    constexpr int RNDS = BLKB / 1024;
    constexpr int NBUF = (NCC > 1) ? 2 : 1;
    constexpr int SMAX = (HALO + NW - 1) / NW;

    __shared__ __align__(16) short sA[HALO][4][68][8];
    __shared__ __align__(16) char  sBraw[NBUF][BLKB];

    const int b  = blockIdx.x;
    const int g  = b & 7;                     // XCD swizzle: group per XCD
    const int r_ = b >> 3;
    const int pt = r_ % NPT;
    const int nt = r_ / NPT;
    const int r0 = pt * ROWS;

    const int t    = threadIdx.x;
    const int wave = t >> 6, lane = t & 63;
    const int l15  = lane & 15, quad = lane >> 4;

    int row_l, ocw;
    if (NW == 8) {
        if (ROWS == 4) { row_l = wave >> 1; ocw = (wave & 1) * (BN / 2); }
        else           { row_l = wave >> 2; ocw = (wave & 3) * (BN / 4); }
    } else {
        row_l = (ROWS == 4) ? wave : (wave & 1);
        ocw   = (ROWS == 4) ? 0 : (wave >> 1) * (BN / 2);
    }

    const size_t gpix = (ICP == 512) ? 0 : ((size_t)g * 4096);
    const char*  wb   = wp + (size_t)((g * NT + nt) * NCC) * BLKB;

    // sA staging: thread -> (col, row-slice); rows j = r2, r2+NW, ...
    const int acol = t & 63;
    const int r2   = t >> 6;

    bf16x8 pre[SMAX][4];

    auto stageA_load = [&](int cc) {
#pragma unroll
        for (int s = 0; s < SMAX; ++s) {
            int j = r2 + s * NW;
            if (j < HALO) {
                int gy = r0 - 1 + j;
                if (gy >= 0 && gy < 64) {
                    const short* sp = inp + ((gpix + gy * 64 + acol) * ICP + cc * 32);
#pragma unroll
                    for (int q = 0; q < 4; ++q)
                        pre[s][q] = *reinterpret_cast<const bf16x8*>(sp + q * 8);
                } else {
#pragma unroll
                    for (int q = 0; q < 4; ++q)
                        pre[s][q] = bf16x8{0, 0, 0, 0, 0, 0, 0, 0};
                }
            }
        }
    };
    auto stageA_write = [&]() {
#pragma unroll
        for (int s = 0; s < SMAX; ++s) {
            int j = r2 + s * NW;
            if (j < HALO) {
#pragma unroll
                for (int q = 0; q < 4; ++q)
                    *reinterpret_cast<bf16x8*>(&sA[j][q][acol + 1][0]) = pre[s][q];
            }
        }
    };
    auto stageB = [&](int cc) {
        const char* wsrc = wb + (size_t)cc * BLKB;
        char* sbb = (char*)sBraw[cc & (NBUF - 1)];
        for (int r = wave; r < RNDS; r += NW)
            gl_lds16(wsrc + r * 1024 + lane * 16, sbb + r * 1024);
    };

    f32x4 acc[OF][4];
#pragma unroll
    for (int o = 0; o < OF; ++o)
#pragma unroll
        for (int p = 0; p < 4; ++p)
#pragma unroll
            for (int r = 0; r < 4; ++r) acc[o][p][r] = 0.f;

    // zero the x-pad column units (col index 0 and 65) once
    if (t < HALO * 8) {
        int row = t >> 3, q = (t >> 1) & 3, cp = (t & 1) ? 65 : 0;
        *reinterpret_cast<bf16x8*>(&sA[row][q][cp][0]) =
            bf16x8{0, 0, 0, 0, 0, 0, 0, 0};
    }

    // prologue: stage phase 0
    stageB(0);
    stageA_load(0);
    stageA_write();

    for (int cc = 0; cc < NCC; ++cc) {
        __syncthreads();               // sB(cc) drained (issued a phase ago)
        if (cc + 1 < NCC) {
            stageB(cc + 1);            // DMA into alternate buffer
            stageA_load(cc + 1);       // global -> regs, no LDS touch
        }
        const bf16x8* sBv = reinterpret_cast<const bf16x8*>(sBraw[cc & (NBUF - 1)]);

#pragma unroll
        for (int dy = 0; dy < 3; ++dy) {
#pragma unroll
            for (int dx = 0; dx < 3; ++dx) {
                bf16x8 pF[4];
#pragma unroll
                for (int p = 0; p < 4; ++p)
                    pF[p] = *reinterpret_cast<const bf16x8*>(
                        &sA[row_l + dy][quad][p * 16 + l15 + dx][0]);
                bf16x8 wF[OF];
#pragma unroll
                for (int o = 0; o < OF; ++o)
                    wF[o] = sBv[((dy * 3 + dx) * 4 + quad) * BN + ocw + o * 16 + l15];
#pragma unroll
                for (int o = 0; o < OF; ++o)
#pragma unroll
                    for (int p = 0; p < 4; ++p)
                        acc[o][p] = __builtin_amdgcn_mfma_f32_16x16x32_bf16(
                            wF[o], pF[p], acc[o][p], 0, 0, 0);
            }
        }
        __syncthreads();               // all reads of sA(cc) done
        if (cc + 1 < NCC) stageA_write();
    }

    // ---- epilogue. C/D: m(oc) = quad*4+reg, n(pixel) = l15.
    const int prow = r0 + row_l;
#pragma unroll
    for (int o = 0; o < OF; ++o)
#pragma unroll
        for (int reg = 0; reg < 4; ++reg) {
            const int ocl = ocw + o * 16 + quad * 4 + reg;
            const int ocg = nt * BN + ocl;
            if (ocg < CREAL) {
                const float bv = bias[g * CREAL + ocg];
                if (PIXMAJ_OUT) {
                    short* outp = (short*)outv;
                    const size_t pixbase = ((size_t)g * 4096 + prow * 64);
#pragma unroll
                    for (int p = 0; p < 4; ++p) {
                        float v = acc[o][p][reg] + bv;
                        if (LEAKY) v = v >= 0.f ? v : 0.1f * v;
                        outp[(pixbase + p * 16 + l15) * (NT * BN) + ocg] = f2bs(v);
                    }
                } else if (OUT_F32) {
                    float* outp = (float*)outv;
                    const size_t base = ((size_t)(g * CREAL + ocg)) * HW + prow * IMG_W;
#pragma unroll
                    for (int p = 0; p < 4; ++p) {
                        float v = acc[o][p][reg] + bv;
                        if (LEAKY) v = v >= 0.f ? v : 0.1f * v;
                        outp[base + p * 16 + l15] = v;
                    }
                } else {
                    short* outp = (short*)outv;
                    const size_t base = ((size_t)(g * CREAL + ocg)) * HW + prow * IMG_W;
#pragma unroll
                    for (int p = 0; p < 4; ++p) {
                        float v = acc[o][p][reg] + bv;
                        if (LEAKY) v = v >= 0.f ? v : 0.1f * v;
                        outp[base + p * 16 + l15] = f2bs(v);
                    }
                }
            }
        }
}

// ---------------------------------------------------------------------------
// Fused softmax-over-groups + bilinear params + warp + combine (fp32 out).
// gar channels come from inp_t rows (stride 512, first 256 entries).
// ---------------------------------------------------------------------------
__global__ __launch_bounds__(256)
void warp_combine_kernel(const float* __restrict__ oa,
                         const short* __restrict__ inp_t,
                         const float* __restrict__ mask,
                         float* __restrict__ out)
{
    __shared__ __align__(16) float4 sWts[8][6][8];
    __shared__ __align__(16) int4   sIdx[8][6][8];

    const int t = threadIdx.x;

    if (t < 48) {
        int lp = t / 6;
        int k  = t % 6;
        int p  = blockIdx.x * 8 + lp;
        int x  = p & 63, y = p >> 6;

        float l[8];
        float m = -1e30f;
#pragma unroll
        for (int g = 0; g < 8; ++g) {
            l[g] = oa[(size_t)(g * 18 + 12 + k) * HW + p];
            m = fmaxf(m, l[g]);
        }
        float s = 0.f;
#pragma unroll
        for (int g = 0; g < 8; ++g) { l[g] = __expf(l[g] - m); s += l[g]; }
        float inv = 1.f / s;

#pragma unroll
        for (int g = 0; g < 8; ++g) {
            float a  = l[g] * inv;
            float ox = oa[(size_t)(g * 18 + 2 * k)     * HW + p];
            float oy = oa[(size_t)(g * 18 + 2 * k + 1) * HW + p];
            float sx = fminf(fmaxf(((float)x + ox) * (64.f / 63.f) - 0.5f, 0.f), 63.f);
            float sy = fminf(fmaxf(((float)y + oy) * (64.f / 63.f) - 0.5f, 0.f), 63.f);
            float fx0 = floorf(sx), fy0 = floorf(sy);
            int   x0 = (int)fx0,    y0i = (int)fy0;
            float wx = sx - fx0,    wy = sy - fy0;
            int   x1 = min(x0 + 1, 63), y1 = min(y0i + 1, 63);
            sWts[lp][k][g] = make_float4(a * (1.f - wy) * (1.f - wx),
                                         a * (1.f - wy) * wx,
                                         a * wy * (1.f - wx),
                                         a * wy * wx);
            sIdx[lp][k][g] = make_int4(y0i * 64 + x0, y0i * 64 + x1,
                                       y1  * 64 + x0, y1  * 64 + x1);
        }
    }
    __syncthreads();

    const int lp = t >> 5;
    const int p  = blockIdx.x * 8 + lp;
    const int c0 = (t & 31) * 8;

    float acc[8];
#pragma unroll
    for (int j = 0; j < 8; ++j) acc[j] = 0.f;

    for (int g = 0; g < 8; ++g) {
        float4 m0 = *reinterpret_cast<const float4*>(mask + g * 256 + c0);
        float4 m1 = *reinterpret_cast<const float4*>(mask + g * 256 + c0 + 4);
        float mk[8] = {m0.x, m0.y, m0.z, m0.w, m1.x, m1.y, m1.z, m1.w};
#pragma unroll
        for (int k = 0; k < 6; ++k) {
            float4 w  = sWts[lp][k][g];
            int4   id = sIdx[lp][k][g];
            ushort8v v00 = *reinterpret_cast<const ushort8v*>(inp_t + (size_t)id.x * 512 + c0);
            ushort8v v01 = *reinterpret_cast<const ushort8v*>(inp_t + (size_t)id.y * 512 + c0);
            ushort8v v10 = *reinterpret_cast<const ushort8v*>(inp_t + (size_t)id.z * 512 + c0);
            ushort8v v11 = *reinterpret_cast<const ushort8v*>(inp_t + (size_t)id.w * 512 + c0);
#pragma unroll
            for (int j = 0; j < 8; ++j) {
                float sv = w.x * bfbits2f(v00[j]) + w.y * bfbits2f(v01[j])
                         + w.z * bfbits2f(v10[j]) + w.w * bfbits2f(v11[j]);
                acc[j] = fmaf(mk[j], sv, acc[j]);
            }
        }
    }
#pragma unroll
    for (int j = 0; j < 8; ++j)
        out[(size_t)(c0 + j) * HW + p] = acc[j];
}

// ---------------------------------------------------------------------------
// Workspace (peak ~25 MB): see round-9 comment (unchanged layout).
// ---------------------------------------------------------------------------
extern "C" void kernel_launch(void* const* d_in, const int* in_sizes, int n_in,
                              void* d_out, int out_size, void* d_ws, size_t ws_size,
                              hipStream_t stream)
{
    (void)in_sizes; (void)n_in; (void)out_size; (void)ws_size;
    const float* gar  = (const float*)d_in[0];
    const float* cond = (const float*)d_in[1];
    const float* mask = (const float*)d_in[2];
    const float* W1   = (const float*)d_in[3];
    const float* b1   = (const float*)d_in[4];
    const float* W2   = (const float*)d_in[5];
    const float* b2   = (const float*)d_in[6];
    const float* W3   = (const float*)d_in[7];
    const float* b3   = (const float*)d_in[8];
    const float* W4   = (const float*)d_in[9];
    const float* b4   = (const float*)d_in[10];
    float* out = (float*)d_out;

    char* ws = (char*)d_ws;
    short* inp_t  = (short*)(ws);
    char*  W1p    = ws + (4u << 20);
    short* hid2_t = (short*)(ws + (4u << 20));          // overlays dead W1p
    short* hid3_t = (short*)(ws + (8u << 20));          // overlays dead W1p
    float* oa     = (float*)(ws + (10u << 20) + (512u << 10));
    char*  W2p    = ws + (14u << 20);
    char*  W3p    = ws + (15u << 20) + (512u << 10);
    char*  W4p    = ws + (16u << 20);
    short* hid1_t = (short*)(ws + (17u << 20));

    // 312 weight-pack blocks + 2048 input-transpose blocks, one launch
    pack_all<<<2360, 256, 0, stream>>>(gar, cond, W1, W2, W3, W4,
                                       inp_t, W1p, W2p, W3p, W4p);

    // conv1: 512->128, ROWS=4, BN=64, OF=2, NT=2, NW=8 (2 waves/SIMD)
    conv_mfma<512, 128, 64, 4, 2, 2, 8, true, true, false>
        <<<256, 512, 0, stream>>>(inp_t, W1p, b1, hid1_t);
    // conv2: 128->64, ROWS=2, BN=64, OF=1, NT=1, NW=8
    conv_mfma<128, 64, 64, 2, 1, 1, 8, true, true, false>
        <<<256, 512, 0, stream>>>(hid1_t, W2p, b2, hid2_t);
    // conv3: 64->32, ROWS=2, BN=32, OF=1, NT=1, NW=4
    conv_mfma<64, 32, 32, 2, 1, 1, 4, true, true, false>
        <<<256, 256, 0, stream>>>(hid2_t, W3p, b3, hid3_t);
    // conv4: 32->18 (pad 32), ROWS=2, BN=32, OF=1, NT=1, NW=4, fp32 ch-major
    conv_mfma<32, 18, 32, 2, 1, 1, 4, false, false, true>
        <<<256, 256, 0, stream>>>(hid3_t, W4p, b4, oa);

    warp_combine_kernel<<<512, 256, 0, stream>>>(oa, inp_t, mask, out);
}

// Round 12
// 202.599 us; speedup vs baseline: 1.1192x; 1.0014x over previous
//
#include <hip/hip_runtime.h>
#include <hip/hip_bf16.h>

typedef __hip_bfloat16 bf16;
typedef unsigned short ushort8v __attribute__((ext_vector_type(8)));
typedef short  s16x4  __attribute__((ext_vector_type(4)));
typedef short  bf16x8 __attribute__((ext_vector_type(8)));   // 8 bf16 (4 VGPRs)
typedef float  f32x4  __attribute__((ext_vector_type(4)));

#define HW 4096
#define IMG_W 64

__device__ __forceinline__ float bfbits2f(unsigned short u) {
    return __uint_as_float(((unsigned int)u) << 16);
}
__device__ __forceinline__ short f2bs(float f) {
    bf16 h = __float2bfloat16(f);
    return *reinterpret_cast<short*>(&h);
}

// async global->LDS, 16B per lane (wave-uniform LDS base + lane*16 scatter).
__device__ __forceinline__ void gl_lds16(const void* g, void* s) {
    __builtin_amdgcn_global_load_lds(
        (const __attribute__((address_space(1))) unsigned int*)g,
        (__attribute__((address_space(3))) unsigned int*)s, 16, 0, 0);
}

// ---------------------------------------------------------------------------
// pack_input (device body): concat(gar,cond) fp32 [512][4096] -> inp_t bf16
// [4096][512] pixel-major. inp_t[:,0:256] doubles as gar_t for warp kernel.
// ---------------------------------------------------------------------------
__device__ void pack_input_dev(const float* __restrict__ gar,
                               const float* __restrict__ cond,
                               short* __restrict__ outp, int bx2, float* tile)
{
    int bx = bx2 & 127;                // px tile (128)
    int by = bx2 >> 7;                 // ch tile (16)
    int tx = threadIdx.x & 31;
    int ty = threadIdx.x >> 5;
#pragma unroll
    for (int i = 0; i < 4; ++i) {
        int c = by * 32 + ty + i * 8;
        const float* src = (c < 256) ? (gar + (size_t)c * HW)
                                     : (cond + (size_t)(c - 256) * HW);
        tile[(ty + i * 8) * 33 + tx] = src[bx * 32 + tx];
    }
    __syncthreads();
#pragma unroll
    for (int i = 0; i < 4; ++i) {
        int p = bx * 32 + ty + i * 8;
        outp[(size_t)p * 512 + by * 32 + tx] = f2bs(tile[tx * 33 + ty + i * 8]);
    }
}

// ---------------------------------------------------------------------------
// pack_w (device body): W fp32 [G][CREAL][CIN][3][3] -> bf16 blocks, layout
// [g][nt][cc][tap 9][q 4][oc BN][8 ic]  (unit = 16 B; q = ic/8 quarter;
// oc zero-padded beyond CREAL). BLKB = 9*4*BN*16 bytes.
// ---------------------------------------------------------------------------
template<int CIN, int CREAL, int BN, int NT>
__device__ void pack_w_dev(const float* __restrict__ wgt, char* __restrict__ wp,
                           int bx, short* sT)
{
    constexpr int NCC  = CIN / 32;
    constexpr int BLKB = 9 * 4 * BN * 16;

    const int t  = threadIdx.x;
    const int cc = bx % NCC;
    const int nt = (bx / NCC) % NT;
    const int g  = bx / (NT * NCC);

    for (int i = t; i < BLKB / 8; i += 256)
        reinterpret_cast<s16x4*>(sT)[i] = s16x4{0, 0, 0, 0};
    __syncthreads();

    int ocmax = CREAL - nt * BN; if (ocmax > BN) ocmax = BN;
    const size_t base = ((size_t)(g * CREAL + nt * BN) * CIN + cc * 32) * 9;
    for (int i = t; i < ocmax * 288; i += 256) {
        int oc = i / 288;
        int r  = i % 288;                      // ic*9 + tap
        int ic = r / 9, tap = r % 9;
        sT[(size_t)(((tap * 4 + (ic >> 3)) * BN + oc) * 8 + (ic & 7))] =
            f2bs(wgt[base + (size_t)oc * CIN * 9 + r]);
    }
    __syncthreads();

    const s16x4* src = reinterpret_cast<const s16x4*>(sT);
    s16x4* dst = reinterpret_cast<s16x4*>(wp + (size_t)bx * BLKB);
    for (int i = t; i < BLKB / 8; i += 256)
        dst[i] = src[i];
}

// All packing in one launch (block-range dispatch; branch is block-uniform).
__global__ __launch_bounds__(256)
void pack_all(const float* __restrict__ gar, const float* __restrict__ cond,
              const float* __restrict__ W1, const float* __restrict__ W2,
              const float* __restrict__ W3, const float* __restrict__ W4,
              short* inp_t, char* W1p, char* W2p, char* W3p, char* W4p)
{
    __shared__ __align__(16) short sbuf[9 * 4 * 64 * 8];   // 36864 B
    int bx = blockIdx.x;
    if (bx < 256)      pack_w_dev<512, 128, 64, 2>(W1, W1p, bx,       sbuf);
    else if (bx < 288) pack_w_dev<128,  64, 64, 1>(W2, W2p, bx - 256, sbuf);
    else if (bx < 304) pack_w_dev< 64,  32, 32, 1>(W3, W3p, bx - 288, sbuf);
    else if (bx < 312) pack_w_dev< 32,  18, 32, 1>(W4, W4p, bx - 304, sbuf);
    else pack_input_dev(gar, cond, inp_t, bx - 312, (float*)sbuf);
}

// ---------------------------------------------------------------------------
// Implicit-GEMM 3x3 SAME conv, bf16 MFMA 16x16x32, conflict-free LDS.
// NW waves/block; PIPE=1: double-buffered sB DMA (prefetch into alt buffer),
// PIPE=0: single sB buffer, DMA issued after the tail barrier (drain exposed
// within the block, hidden by the co-resident second block per CU).
// Wave mapping:
//   NW=8, ROWS=4: wave -> (row = wave>>1, oc-half = wave&1),    OF=BN/32
//   NW=8, ROWS=2: wave -> (row = wave>>2, oc-quarter = wave&3), OF=BN/64
//   NW=4, ROWS=4: wave -> row, full BN                          OF=BN/16
//   NW=4, ROWS=2: wave -> (row = wave&1, oc-half = wave>>1)     OF=BN/32
// ---------------------------------------------------------------------------
template<int ICP, int CREAL, int BN, int ROWS, int OF, int NT, int NW, int PIPE,
         bool PIXMAJ_OUT, bool LEAKY, bool OUT_F32>
__global__ __launch_bounds__(NW * 64, 2)
void conv_mfma(const short* __restrict__ inp, const char* __restrict__ wp,
               const float* __restrict__ bias, void* __restrict__ outv)
{
    constexpr int NCC  = ICP / 32;
    constexpr int HALO = ROWS + 2;
    constexpr int NPT  = 4096 / (ROWS * 64);
    constexpr int BLKB = 9 * 4 * BN * 16;
    constexpr int RNDS = BLKB / 1024;
    constexpr int NBUF = (PIPE && NCC > 1) ? 2 : 1;
    constexpr int SMAX = (HALO + NW - 1) / NW;

    __shared__ __align__(16) short sA[HALO][4][68][8];
    __shared__ __align__(16) char  sBraw[NBUF][BLKB];

    const int b  = blockIdx.x;
    const int g  = b & 7;                     // XCD swizzle: group per XCD
    const int r_ = b >> 3;
    const int pt = r_ % NPT;
    const int nt = r_ / NPT;
    const int r0 = pt * ROWS;

    const int t    = threadIdx.x;
    const int wave = t >> 6, lane = t & 63;
    const int l15  = lane & 15, quad = lane >> 4;

    int row_l, ocw;
    if (NW == 8) {
        if (ROWS == 4) { row_l = wave >> 1; ocw = (wave & 1) * (BN / 2); }
        else           { row_l = wave >> 2; ocw = (wave & 3) * (BN / 4); }
    } else {
        row_l = (ROWS == 4) ? wave : (wave & 1);
        ocw   = (ROWS == 4) ? 0 : (wave >> 1) * (BN / 2);
    }

    const size_t gpix = (ICP == 512) ? 0 : ((size_t)g * 4096);
    const char*  wb   = wp + (size_t)((g * NT + nt) * NCC) * BLKB;

    // sA staging: thread -> (col, row-slice); rows j = r2, r2+NW, ...
    const int acol = t & 63;
    const int r2   = t >> 6;

    bf16x8 pre[SMAX][4];

    auto stageA_load = [&](int cc) {
#pragma unroll
        for (int s = 0; s < SMAX; ++s) {
            int j = r2 + s * NW;
            if (j < HALO) {
                int gy = r0 - 1 + j;
                if (gy >= 0 && gy < 64) {
                    const short* sp = inp + ((gpix + gy * 64 + acol) * ICP + cc * 32);
#pragma unroll
                    for (int q = 0; q < 4; ++q)
                        pre[s][q] = *reinterpret_cast<const bf16x8*>(sp + q * 8);
                } else {
#pragma unroll
                    for (int q = 0; q < 4; ++q)
                        pre[s][q] = bf16x8{0, 0, 0, 0, 0, 0, 0, 0};
                }
            }
        }
    };
    auto stageA_write = [&]() {
#pragma unroll
        for (int s = 0; s < SMAX; ++s) {
            int j = r2 + s * NW;
            if (j < HALO) {
#pragma unroll
                for (int q = 0; q < 4; ++q)
                    *reinterpret_cast<bf16x8*>(&sA[j][q][acol + 1][0]) = pre[s][q];
            }
        }
    };
    auto stageB = [&](int cc) {
        const char* wsrc = wb + (size_t)cc * BLKB;
        char* sbb = (char*)sBraw[(NBUF == 2) ? (cc & 1) : 0];
        for (int r = wave; r < RNDS; r += NW)
            gl_lds16(wsrc + r * 1024 + lane * 16, sbb + r * 1024);
    };

    f32x4 acc[OF][4];
#pragma unroll
    for (int o = 0; o < OF; ++o)
#pragma unroll
        for (int p = 0; p < 4; ++p)
#pragma unroll
            for (int r = 0; r < 4; ++r) acc[o][p][r] = 0.f;

    // zero the x-pad column units (col index 0 and 65) once
    if (t < HALO * 8) {
        int row = t >> 3, q = (t >> 1) & 3, cp = (t & 1) ? 65 : 0;
        *reinterpret_cast<bf16x8*>(&sA[row][q][cp][0]) =
            bf16x8{0, 0, 0, 0, 0, 0, 0, 0};
    }

    // prologue: stage phase 0
    stageB(0);
    stageA_load(0);
    stageA_write();

    for (int cc = 0; cc < NCC; ++cc) {
        __syncthreads();               // sB(cc) drained, sA(cc) visible
        if (cc + 1 < NCC) {
            if (PIPE) stageB(cc + 1);  // dbuf: DMA into alternate buffer now
            stageA_load(cc + 1);       // global -> regs, no LDS touch
        }
        const bf16x8* sBv = reinterpret_cast<const bf16x8*>(
            sBraw[(NBUF == 2) ? (cc & 1) : 0]);

#pragma unroll
        for (int dy = 0; dy < 3; ++dy) {
#pragma unroll
            for (int dx = 0; dx < 3; ++dx) {
                bf16x8 pF[4];
#pragma unroll
                for (int p = 0; p < 4; ++p)
                    pF[p] = *reinterpret_cast<const bf16x8*>(
                        &sA[row_l + dy][quad][p * 16 + l15 + dx][0]);
                bf16x8 wF[OF];
#pragma unroll
                for (int o = 0; o < OF; ++o)
                    wF[o] = sBv[((dy * 3 + dx) * 4 + quad) * BN + ocw + o * 16 + l15];
#pragma unroll
                for (int o = 0; o < OF; ++o)
#pragma unroll
                    for (int p = 0; p < 4; ++p)
                        acc[o][p] = __builtin_amdgcn_mfma_f32_16x16x32_bf16(
                            wF[o], pF[p], acc[o][p], 0, 0, 0);
            }
        }
        __syncthreads();               // all reads of sA(cc)/sB(cc) done
        if (cc + 1 < NCC) {
            if (!PIPE) stageB(cc + 1); // single-buf: DMA into the freed buffer
            stageA_write();
        }
    }

    // ---- epilogue. C/D: m(oc) = quad*4+reg, n(pixel) = l15.
    const int prow = r0 + row_l;
#pragma unroll
    for (int o = 0; o < OF; ++o)
#pragma unroll
        for (int reg = 0; reg < 4; ++reg) {
            const int ocl = ocw + o * 16 + quad * 4 + reg;
            const int ocg = nt * BN + ocl;
            if (ocg < CREAL) {
                const float bv = bias[g * CREAL + ocg];
                if (PIXMAJ_OUT) {
                    short* outp = (short*)outv;
                    const size_t pixbase = ((size_t)g * 4096 + prow * 64);
#pragma unroll
                    for (int p = 0; p < 4; ++p) {
                        float v = acc[o][p][reg] + bv;
                        if (LEAKY) v = v >= 0.f ? v : 0.1f * v;
                        outp[(pixbase + p * 16 + l15) * (NT * BN) + ocg] = f2bs(v);
                    }
                } else if (OUT_F32) {
                    float* outp = (float*)outv;
                    const size_t base = ((size_t)(g * CREAL + ocg)) * HW + prow * IMG_W;
#pragma unroll
                    for (int p = 0; p < 4; ++p) {
                        float v = acc[o][p][reg] + bv;
                        if (LEAKY) v = v >= 0.f ? v : 0.1f * v;
                        outp[base + p * 16 + l15] = v;
                    }
                } else {
                    short* outp = (short*)outv;
                    const size_t base = ((size_t)(g * CREAL + ocg)) * HW + prow * IMG_W;
#pragma unroll
                    for (int p = 0; p < 4; ++p) {
                        float v = acc[o][p][reg] + bv;
                        if (LEAKY) v = v >= 0.f ? v : 0.1f * v;
                        outp[base + p * 16 + l15] = f2bs(v);
                    }
                }
            }
        }
}

// ---------------------------------------------------------------------------
// Fused softmax-over-groups + bilinear params + warp + combine (fp32 out).
// gar channels come from inp_t rows (stride 512, first 256 entries).
// ---------------------------------------------------------------------------
__global__ __launch_bounds__(256)
void warp_combine_kernel(const float* __restrict__ oa,
                         const short* __restrict__ inp_t,
                         const float* __restrict__ mask,
                         float* __restrict__ out)
{
    __shared__ __align__(16) float4 sWts[8][6][8];
    __shared__ __align__(16) int4   sIdx[8][6][8];

    const int t = threadIdx.x;

    if (t < 48) {
        int lp = t / 6;
        int k  = t % 6;
        int p  = blockIdx.x * 8 + lp;
        int x  = p & 63, y = p >> 6;

        float l[8];
        float m = -1e30f;
#pragma unroll
        for (int g = 0; g < 8; ++g) {
            l[g] = oa[(size_t)(g * 18 + 12 + k) * HW + p];
            m = fmaxf(m, l[g]);
        }
        float s = 0.f;
#pragma unroll
        for (int g = 0; g < 8; ++g) { l[g] = __expf(l[g] - m); s += l[g]; }
        float inv = 1.f / s;

#pragma unroll
        for (int g = 0; g < 8; ++g) {
            float a  = l[g] * inv;
            float ox = oa[(size_t)(g * 18 + 2 * k)     * HW + p];
            float oy = oa[(size_t)(g * 18 + 2 * k + 1) * HW + p];
            float sx = fminf(fmaxf(((float)x + ox) * (64.f / 63.f) - 0.5f, 0.f), 63.f);
            float sy = fminf(fmaxf(((float)y + oy) * (64.f / 63.f) - 0.5f, 0.f), 63.f);
            float fx0 = floorf(sx), fy0 = floorf(sy);
            int   x0 = (int)fx0,    y0i = (int)fy0;
            float wx = sx - fx0,    wy = sy - fy0;
            int   x1 = min(x0 + 1, 63), y1 = min(y0i + 1, 63);
            sWts[lp][k][g] = make_float4(a * (1.f - wy) * (1.f - wx),
                                         a * (1.f - wy) * wx,
                                         a * wy * (1.f - wx),
                                         a * wy * wx);
            sIdx[lp][k][g] = make_int4(y0i * 64 + x0, y0i * 64 + x1,
                                       y1  * 64 + x0, y1  * 64 + x1);
        }
    }
    __syncthreads();

    const int lp = t >> 5;
    const int p  = blockIdx.x * 8 + lp;
    const int c0 = (t & 31) * 8;

    float acc[8];
#pragma unroll
    for (int j = 0; j < 8; ++j) acc[j] = 0.f;

    for (int g = 0; g < 8; ++g) {
        float4 m0 = *reinterpret_cast<const float4*>(mask + g * 256 + c0);
        float4 m1 = *reinterpret_cast<const float4*>(mask + g * 256 + c0 + 4);
        float mk[8] = {m0.x, m0.y, m0.z, m0.w, m1.x, m1.y, m1.z, m1.w};
#pragma unroll
        for (int k = 0; k < 6; ++k) {
            float4 w  = sWts[lp][k][g];
            int4   id = sIdx[lp][k][g];
            ushort8v v00 = *reinterpret_cast<const ushort8v*>(inp_t + (size_t)id.x * 512 + c0);
            ushort8v v01 = *reinterpret_cast<const ushort8v*>(inp_t + (size_t)id.y * 512 + c0);
            ushort8v v10 = *reinterpret_cast<const ushort8v*>(inp_t + (size_t)id.z * 512 + c0);
            ushort8v v11 = *reinterpret_cast<const ushort8v*>(inp_t + (size_t)id.w * 512 + c0);
#pragma unroll
            for (int j = 0; j < 8; ++j) {
                float sv = w.x * bfbits2f(v00[j]) + w.y * bfbits2f(v01[j])
                         + w.z * bfbits2f(v10[j]) + w.w * bfbits2f(v11[j]);
                acc[j] = fmaf(mk[j], sv, acc[j]);
            }
        }
    }
#pragma unroll
    for (int j = 0; j < 8; ++j)
        out[(size_t)(c0 + j) * HW + p] = acc[j];
}

// ---------------------------------------------------------------------------
// Workspace (peak ~25 MB): see round-9 comment (unchanged layout).
// ---------------------------------------------------------------------------
extern "C" void kernel_launch(void* const* d_in, const int* in_sizes, int n_in,
                              void* d_out, int out_size, void* d_ws, size_t ws_size,
                              hipStream_t stream)
{
    (void)in_sizes; (void)n_in; (void)out_size; (void)ws_size;
    const float* gar  = (const float*)d_in[0];
    const float* cond = (const float*)d_in[1];
    const float* mask = (const float*)d_in[2];
    const float* W1   = (const float*)d_in[3];
    const float* b1   = (const float*)d_in[4];
    const float* W2   = (const float*)d_in[5];
    const float* b2   = (const float*)d_in[6];
    const float* W3   = (const float*)d_in[7];
    const float* b3   = (const float*)d_in[8];
    const float* W4   = (const float*)d_in[9];
    const float* b4   = (const float*)d_in[10];
    float* out = (float*)d_out;

    char* ws = (char*)d_ws;
    short* inp_t  = (short*)(ws);
    char*  W1p    = ws + (4u << 20);
    short* hid2_t = (short*)(ws + (4u << 20));          // overlays dead W1p
    short* hid3_t = (short*)(ws + (8u << 20));          // overlays dead W1p
    float* oa     = (float*)(ws + (10u << 20) + (512u << 10));
    char*  W2p    = ws + (14u << 20);
    char*  W3p    = ws + (15u << 20) + (512u << 10);
    char*  W4p    = ws + (16u << 20);
    short* hid1_t = (short*)(ws + (17u << 20));

    // 312 weight-pack blocks + 2048 input-transpose blocks, one launch
    pack_all<<<2360, 256, 0, stream>>>(gar, cond, W1, W2, W3, W4,
                                       inp_t, W1p, W2p, W3p, W4p);

    // conv1: 512->128, ROWS=2 tile (128px x 64oc), NW=4, PIPE=0 single-buf,
    // grid 512 -> 2 blocks/CU (LDS 54.3 KB): cross-block latency hiding.
    conv_mfma<512, 128, 64, 2, 2, 2, 4, 0, true, true, false>
        <<<512, 256, 0, stream>>>(inp_t, W1p, b1, hid1_t);
    // conv2: 128->64, ROWS=2, BN=64, OF=1, NT=1, NW=8, PIPE=1 (unchanged)
    conv_mfma<128, 64, 64, 2, 1, 1, 8, 1, true, true, false>
        <<<256, 512, 0, stream>>>(hid1_t, W2p, b2, hid2_t);
    // conv3: 64->32, ROWS=2, BN=32, OF=1, NT=1, NW=4, PIPE=1 (unchanged)
    conv_mfma<64, 32, 32, 2, 1, 1, 4, 1, true, true, false>
        <<<256, 256, 0, stream>>>(hid2_t, W3p, b3, hid3_t);
    // conv4: 32->18 (pad 32), ROWS=2, BN=32, OF=1, NT=1, NW=4 (unchanged)
    conv_mfma<32, 18, 32, 2, 1, 1, 4, 1, false, false, true>
        <<<256, 256, 0, stream>>>(hid3_t, W4p, b4, oa);

    warp_combine_kernel<<<512, 256, 0, stream>>>(oa, inp_t, mask, out);
}